// Round 2
// baseline (225.358 us; speedup 1.0000x reference)
//
#include <hip/hip_runtime.h>

// cov = R * diag(s^2) * R^T per gaussian (COLMAP quat convention, no normalize).
// Memory-bound: 28 B in + 36 B out per gaussian (256 MB total @ N=4M).
// LDS-staged output -> float4 nontemporal store sweeps (streaming writes).

typedef float v4f __attribute__((ext_vector_type(4)));

__global__ __launch_bounds__(256) void gaussian_cov_kernel(
    const float4* __restrict__ quat,   // [N] as (w,x,y,z)
    const float*  __restrict__ scales, // [N*3]
    float*        __restrict__ out,    // [N*9]
    int N) {
    __shared__ float lds[256 * 9];   // 9 KiB

    const int t = threadIdx.x;
    const int i = blockIdx.x * 256 + t;

    if (i < N) {
        const float4 q = quat[i];
        const float w = q.x, x = q.y, y = q.z, z = q.w;
        const float sx = scales[3 * i + 0];
        const float sy = scales[3 * i + 1];
        const float sz = scales[3 * i + 2];

        const float xx = 2.0f * x * x, yy = 2.0f * y * y, zz = 2.0f * z * z;
        const float xy = 2.0f * x * y, xz = 2.0f * x * z, yz = 2.0f * y * z;
        const float wx = 2.0f * w * x, wy = 2.0f * w * y, wz = 2.0f * w * z;

        const float R00 = 1.0f - yy - zz, R01 = xy - wz, R02 = xz + wy;
        const float R10 = xy + wz, R11 = 1.0f - xx - zz, R12 = yz - wx;
        const float R20 = xz - wy, R21 = yz + wx, R22 = 1.0f - xx - yy;

        const float s2x = sx * sx, s2y = sy * sy, s2z = sz * sz;

        const float c00 = R00 * R00 * s2x + R01 * R01 * s2y + R02 * R02 * s2z;
        const float c01 = R00 * R10 * s2x + R01 * R11 * s2y + R02 * R12 * s2z;
        const float c02 = R00 * R20 * s2x + R01 * R21 * s2y + R02 * R22 * s2z;
        const float c11 = R10 * R10 * s2x + R11 * R11 * s2y + R12 * R12 * s2z;
        const float c12 = R10 * R20 * s2x + R11 * R21 * s2y + R12 * R22 * s2z;
        const float c22 = R20 * R20 * s2x + R21 * R21 * s2y + R22 * R22 * s2z;

        float* l = &lds[t * 9];
        l[0] = c00; l[1] = c01; l[2] = c02;
        l[3] = c01; l[4] = c11; l[5] = c12;
        l[6] = c02; l[7] = c12; l[8] = c22;
    }

    __syncthreads();

    const int base  = blockIdx.x * (256 * 9);   // max ~36M, fits int
    const int total = N * 9;

    if (base + 256 * 9 <= total) {
        // Full block: 2304 floats = 576 float4. Branchless vectorized sweep.
        v4f* out4 = (v4f*)(out + base);          // base*4 bytes, 16B-aligned
        const v4f* l4 = (const v4f*)lds;
#pragma unroll
        for (int r = 0; r < 2; ++r) {
            const int idx = r * 256 + t;
            __builtin_nontemporal_store(l4[idx], &out4[idx]);
        }
        if (t < 64) {
            const int idx = 512 + t;
            __builtin_nontemporal_store(l4[idx], &out4[idx]);
        }
    } else {
        // Tail block (not hit at N=4M, kept for generality).
#pragma unroll
        for (int r = 0; r < 9; ++r) {
            const int idx = r * 256 + t;
            if (base + idx < total) out[base + idx] = lds[idx];
        }
    }
}

extern "C" void kernel_launch(void* const* d_in, const int* in_sizes, int n_in,
                              void* d_out, int out_size, void* d_ws, size_t ws_size,
                              hipStream_t stream) {
    const float4* quat   = (const float4*)d_in[0];
    const float*  scales = (const float*)d_in[1];
    float*        out    = (float*)d_out;
    const int N = in_sizes[0] / 4;
    const int blocks = (N + 255) / 256;
    gaussian_cov_kernel<<<blocks, 256, 0, stream>>>(quat, scales, out, N);
}